// Round 4
// baseline (446.638 us; speedup 1.0000x reference)
//
#include <hip/hip_runtime.h>

#define LOG2E 1.442695040888963f

// Two batch elements per 64-lane wave (1024 blocks, 1 wave/SIMD), half-step
// skewed so each stream's LDS h-broadcast latency hides under the other
// stream's FMA issue.
//
// Row mapping (rows 0..103 = i,f,g,o): lane l<52 owns row l (a0) and row l+52 (a1).
//   l<26:        a0 = i_l (sigmoid), a1 = g_l (tanh)
//   l in[26,52): a0 = f_{l-26} (sigmoid), a1 = o_{l-26} (sigmoid)
// Cell state c_j lives in lane 26+j (the f,o lane): only i*g crosses lanes
// (one ds_bpermute); c-update, tanh(c), h = o*tanh(c) are lane-local there.
// h_j written by lane 26+j to hbuf[j]; other lanes write a junk zone [26..63].
// P and W_hh prescaled by the exp2 multipliers (-log2e / -2log2e), fp32.
// Single-wave workgroup => in-order DS pipe, no barriers in the T-loop.
__launch_bounds__(64, 1)
__global__ void lstm_char_kernel(const int* __restrict__ x,      // [B,T] int32
                                 const float* __restrict__ E,     // [26,26]
                                 const float* __restrict__ W_ih,  // [104,26]
                                 const float* __restrict__ W_hh,  // [104,26]
                                 const float* __restrict__ b_ih,  // [104]
                                 const float* __restrict__ b_hh,  // [104]
                                 const float* __restrict__ W_lin, // [26,26]
                                 const float* __restrict__ b_lin, // [26]
                                 float* __restrict__ out,         // [B,26]
                                 int T)
{
    constexpr int H = 26;

    __shared__ float P[27][104];          // prescaled input projection (+biases)
    __shared__ float Ebuf[676];
    __shared__ int   chars0[1026];        // premultiplied P-row byte offsets
    __shared__ int   chars1[1026];
    __shared__ __align__(16) float hbuf0[64];
    __shared__ __align__(16) float hbuf1[64];

    const int l = threadIdx.x;
    const size_t b0 = 2 * (size_t)blockIdx.x;
    const size_t b1 = b0 + 1;
    const bool act = (l < 52);
    const int r0 = act ? l : 0;
    const int r1 = act ? l + 52 : 0;

    // ---- stage E, both char sequences, zero h ----
    for (int i = l; i < 676; i += 64) Ebuf[i] = E[i];
    for (int t = l; t < T; t += 64) {
        chars0[t] = x[b0 * T + t] * 416;   // 104 floats * 4 B per P row
        chars1[t] = x[b1 * T + t] * 416;
    }
    if (l < 2) { chars0[1024 + l] = 0; chars1[1024 + l] = 0; }
    hbuf0[l] = 0.0f;
    hbuf1[l] = 0.0f;

    // per-lane exp2 prescale: row0 (i or f) always sigmoid; row1 tanh (l<26) else sigmoid
    const float m0 = -LOG2E;
    const float m1 = (l < 26) ? (-2.0f * LOG2E) : (-LOG2E);
    const float s1 = (l < 26) ? 2.0f : 1.0f;
    const float d1 = (l < 26) ? -1.0f : 0.0f;

    // ---- prescaled fp32 recurrent weights (shared by both streams) ----
    float wh0[H], wh1[H];
    {
        float wi0[H], wi1[H];
        #pragma unroll
        for (int k = 0; k < H; ++k) {
            wi0[k] = W_ih[r0 * H + k];
            wi1[k] = W_ih[r1 * H + k];
            wh0[k] = W_hh[r0 * H + k] * m0;
            wh1[k] = W_hh[r1 * H + k] * m1;
        }
        const float bias0 = b_ih[r0] + b_hh[r0];
        const float bias1 = b_ih[r1] + b_hh[r1];
        __syncthreads();
        // P[ch][row] = m_row * (E[ch]·W_ih[row] + b_ih[row] + b_hh[row])
        for (int ch = 0; ch < 26; ++ch) {
            float a0 = bias0, a1 = bias1;
            #pragma unroll
            for (int k = 0; k < H; ++k) {
                float e = Ebuf[ch * H + k];
                a0 = fmaf(wi0[k], e, a0);
                a1 = fmaf(wi1[k], e, a1);
            }
            if (act) { P[ch][l] = a0 * m0; P[ch][52 + l] = a1 * m1; }
        }
    }
    __syncthreads();

    const int bpaddr = ((l - 26) & 63) << 2;   // lane l pulls from lane l-26
    const int hidx   = (l - 26) & 63;          // 26..51 -> 0..25; others -> junk zone

    // ---- pipeline prologue ----
    const char* Pb = (const char*)&P[0][0];
    int pf0 = chars0[1];
    int pf1 = chars1[1];
    float pa00, pa01, pa10, pa11;
    { const float* r = (const float*)(Pb + chars0[0]); pa00 = r[l]; pa01 = r[l + 52]; }
    { const float* r = (const float*)(Pb + chars1[0]); pa10 = r[l]; pa11 = r[l + 52]; }
    float c0 = 0.0f, c1 = 0.0f;

    // stream0's h for t=0 (zeros) loaded ahead; stream1's loaded inside the loop
    float hr0[28];
    #pragma unroll
    for (int q = 0; q < 7; ++q) {
        float4 v = ((const float4*)hbuf0)[q];
        hr0[4*q] = v.x; hr0[4*q+1] = v.y; hr0[4*q+2] = v.z; hr0[4*q+3] = v.w;
    }

    for (int t = 0; t < T; ++t) {
        // ---- issue stream1's h read (latency hides under stream0 compute) ----
        float hr1[28];
        #pragma unroll
        for (int q = 0; q < 7; ++q) {
            float4 v = ((const float4*)hbuf1)[q];
            hr1[4*q] = v.x; hr1[4*q+1] = v.y; hr1[4*q+2] = v.z; hr1[4*q+3] = v.w;
        }
        // prefetch P rows for t+1 and char offsets for t+2 (independent)
        const float* Pn0 = (const float*)(Pb + pf0);
        const float* Pn1 = (const float*)(Pb + pf1);
        float q00 = Pn0[l], q01 = Pn0[l + 52];
        float q10 = Pn1[l], q11 = Pn1[l + 52];
        int pf0n = chars0[t + 2];
        int pf1n = chars1[t + 2];

        // ================= stream 0 compute (uses hr0) =================
        {
            float u0 = pa00, u1 = 0.0f, u2 = pa01, u3 = 0.0f;
            #pragma unroll
            for (int k = 0; k < H; k += 2) {
                u0 = fmaf(wh0[k],     hr0[k],     u0);
                u1 = fmaf(wh0[k + 1], hr0[k + 1], u1);
                u2 = fmaf(wh1[k],     hr0[k],     u2);
                u3 = fmaf(wh1[k + 1], hr0[k + 1], u3);
            }
            const float a0 = u0 + u1;
            const float a1 = u2 + u3;
            float y0 = __builtin_amdgcn_rcpf(1.0f + __builtin_amdgcn_exp2f(a0));
            float y1 = fmaf(__builtin_amdgcn_rcpf(1.0f + __builtin_amdgcn_exp2f(a1)),
                            s1, d1);
            float pr = y0 * y1;                               // i*g (lanes<26)
            float pp = __int_as_float(
                __builtin_amdgcn_ds_bpermute(bpaddr, __float_as_int(pr)));
            c0 = fmaf(y0, c0, pp);                            // f*c + i*g (lanes 26..51)
            float th = fmaf(__builtin_amdgcn_rcpf(
                                1.0f + __builtin_amdgcn_exp2f(c0 * (-2.0f * LOG2E))),
                            2.0f, -1.0f);
            hbuf0[hidx] = y1 * th;                            // o * tanh(c)
        }

        // ---- issue stream0's h read for t+1 (hides under stream1 compute) ----
        #pragma unroll
        for (int q = 0; q < 7; ++q) {
            float4 v = ((const float4*)hbuf0)[q];
            hr0[4*q] = v.x; hr0[4*q+1] = v.y; hr0[4*q+2] = v.z; hr0[4*q+3] = v.w;
        }

        // ================= stream 1 compute (uses hr1) =================
        {
            float u0 = pa10, u1 = 0.0f, u2 = pa11, u3 = 0.0f;
            #pragma unroll
            for (int k = 0; k < H; k += 2) {
                u0 = fmaf(wh0[k],     hr1[k],     u0);
                u1 = fmaf(wh0[k + 1], hr1[k + 1], u1);
                u2 = fmaf(wh1[k],     hr1[k],     u2);
                u3 = fmaf(wh1[k + 1], hr1[k + 1], u3);
            }
            const float a0 = u0 + u1;
            const float a1 = u2 + u3;
            float y0 = __builtin_amdgcn_rcpf(1.0f + __builtin_amdgcn_exp2f(a0));
            float y1 = fmaf(__builtin_amdgcn_rcpf(1.0f + __builtin_amdgcn_exp2f(a1)),
                            s1, d1);
            float pr = y0 * y1;
            float pp = __int_as_float(
                __builtin_amdgcn_ds_bpermute(bpaddr, __float_as_int(pr)));
            c1 = fmaf(y0, c1, pp);
            float th = fmaf(__builtin_amdgcn_rcpf(
                                1.0f + __builtin_amdgcn_exp2f(c1 * (-2.0f * LOG2E))),
                            2.0f, -1.0f);
            hbuf1[hidx] = y1 * th;
        }

        pa00 = q00; pa01 = q01; pa10 = q10; pa11 = q11;
        pf0 = pf0n; pf1 = pf1n;
    }

    __syncthreads();

    // ---- final linear for both streams ----
    if (l < H) {
        float acc0 = b_lin[l], acc1 = b_lin[l];
        #pragma unroll
        for (int k = 0; k < H; ++k) {
            float w = W_lin[l * H + k];
            acc0 = fmaf(w, hbuf0[k], acc0);
            acc1 = fmaf(w, hbuf1[k], acc1);
        }
        out[b0 * H + l] = acc0;
        out[b1 * H + l] = acc1;
    }
}

extern "C" void kernel_launch(void* const* d_in, const int* in_sizes, int n_in,
                              void* d_out, int out_size, void* d_ws, size_t ws_size,
                              hipStream_t stream) {
    const int*   x     = (const int*)d_in[0];
    const float* E     = (const float*)d_in[1];
    const float* W_ih  = (const float*)d_in[2];
    const float* W_hh  = (const float*)d_in[3];
    const float* b_ih  = (const float*)d_in[4];
    const float* b_hh  = (const float*)d_in[5];
    const float* W_lin = (const float*)d_in[6];
    const float* b_lin = (const float*)d_in[7];
    float* out = (float*)d_out;

    const int T = 1024;
    const int B = in_sizes[0] / T;   // 2048

    lstm_char_kernel<<<B / 2, 64, 0, stream>>>(x, E, W_ih, W_hh, b_ih, b_hh,
                                               W_lin, b_lin, out, T);
}

// Round 5
// 282.324 us; speedup vs baseline: 1.5820x; 1.5820x over previous
//
#include <hip/hip_runtime.h>

#define LOG2E 1.442695040888963f

typedef float f32x2 __attribute__((ext_vector_type(2)));
typedef float f32x4 __attribute__((ext_vector_type(4)));

// packed fp32 FMA / MUL (VOP3P, full IEEE fp32 on both halves)
static __device__ __forceinline__ void pkfma(f32x2& acc, f32x2 a, f32x2 b) {
    asm("v_pk_fma_f32 %0, %1, %2, %0" : "+v"(acc) : "v"(a), "v"(b));
}
static __device__ __forceinline__ void pkmul(f32x2& d, f32x2 a, f32x2 b) {
    asm("v_pk_mul_f32 %0, %1, %2" : "=v"(d) : "v"(a), "v"(b));
}

// One batch element per 64-lane wave (2048 blocks, 2 waves/SIMD).
// Rows 0..103 = gates i,f,g,o. Lane l<52 owns row l (dot0) and row l+52 (dot1):
//   l<26:        dot0 = i_l (sigmoid), dot1 = g_l (tanh)
//   l in[26,52): dot0 = f_{l-26} (sigmoid), dot1 = o_{l-26} (sigmoid)
// Cell state c_j lives in lane 26+j: only i*g crosses lanes (one ds_bpermute);
// the c update, tanh(c) and h = o*tanh(c) are lane-local there. Lane 26+j
// writes h_j to hbuf[j]; other lanes write a junk zone [26..63].
// P and W_hh prescaled by the exp2 multipliers (-log2e / -2log2e), fp32.
// P stored as interleaved pairs {row_l, row_{l+52}} -> one ds_read_b64/step.
// Single-wave workgroup => in-order DS pipe, no barriers in the T-loop.
__launch_bounds__(64, 2)
__global__ void lstm_char_kernel(const int* __restrict__ x,      // [B,T] int32
                                 const float* __restrict__ E,     // [26,26]
                                 const float* __restrict__ W_ih,  // [104,26]
                                 const float* __restrict__ W_hh,  // [104,26]
                                 const float* __restrict__ b_ih,  // [104]
                                 const float* __restrict__ b_hh,  // [104]
                                 const float* __restrict__ W_lin, // [26,26]
                                 const float* __restrict__ b_lin, // [26]
                                 float* __restrict__ out,         // [B,26]
                                 int T)
{
    constexpr int H = 26;

    __shared__ __align__(16) f32x2 P[27][52];   // prescaled, pair-interleaved
    __shared__ float Ebuf[676];
    __shared__ int   chars[1026];               // premultiplied byte offsets
    __shared__ __align__(16) float hbuf[64];

    const int b = blockIdx.x;
    const int l = threadIdx.x;
    const bool act = (l < 52);
    const int r0 = act ? l : 0;
    const int r1 = act ? l + 52 : 0;

    // ---- stage E, char sequence (as P-row byte offsets: 52 pairs * 8 B = 416) ----
    for (int i = l; i < 676; i += 64) Ebuf[i] = E[i];
    for (int t = l; t < T; t += 64) chars[t] = x[(size_t)b * T + t] * 416;
    if (l < 2) chars[1024 + l] = 0;
    hbuf[l] = 0.0f;

    // per-lane exp2 prescale: dot0 (i or f) sigmoid; dot1 tanh (l<26) else sigmoid
    const float m0 = -LOG2E;
    const float m1 = (l < 26) ? (-2.0f * LOG2E) : (-LOG2E);
    const float s1 = (l < 26) ? 2.0f : 1.0f;
    const float d1 = (l < 26) ? -1.0f : 0.0f;

    // ---- prescaled fp32 recurrent weights as packed pairs ----
    f32x2 wh0p[13], wh1p[13];
    #pragma unroll
    for (int k = 0; k < 13; ++k) {
        wh0p[k] = f32x2{W_hh[r0 * H + 2 * k] * m0, W_hh[r0 * H + 2 * k + 1] * m0};
        wh1p[k] = f32x2{W_hh[r1 * H + 2 * k] * m1, W_hh[r1 * H + 2 * k + 1] * m1};
    }

    // ---- build prescaled pair-interleaved P table ----
    {
        float wi0[H], wi1[H];
        #pragma unroll
        for (int k = 0; k < H; ++k) {
            wi0[k] = W_ih[r0 * H + k];
            wi1[k] = W_ih[r1 * H + k];
        }
        const float bias0 = b_ih[r0] + b_hh[r0];
        const float bias1 = b_ih[r1] + b_hh[r1];
        __syncthreads();
        for (int ch = 0; ch < 26; ++ch) {
            float a0 = bias0, a1 = bias1;
            #pragma unroll
            for (int k = 0; k < H; ++k) {
                float e = Ebuf[ch * H + k];
                a0 = fmaf(wi0[k], e, a0);
                a1 = fmaf(wi1[k], e, a1);
            }
            if (act) P[ch][l] = f32x2{a0 * m0, a1 * m1};
        }
    }
    __syncthreads();

    const int bpaddr = ((l - 26) & 63) << 2;   // lane l pulls from lane l-26
    const int hidx   = (l - 26) & 63;          // 26..51 -> 0..25; others -> junk
    const char* Pb = (const char*)&P[0][0];
    const int lane8 = l << 3;

    // ---- pipeline prologue ----
    int poffn = chars[1];
    f32x2 pa = *(const f32x2*)(Pb + chars[0] + lane8);
    float c = 0.0f;

    #pragma unroll 2
    for (int t = 0; t < T; ++t) {
        // h broadcast: 13 uniform-address b64 reads (packed pairs)
        f32x2 hp[13];
        #pragma unroll
        for (int q = 0; q < 13; ++q) hp[q] = ((const f32x2*)hbuf)[q];

        // prefetch P pair for t+1, char offset for t+2 (independent)
        f32x2 pn = *(const f32x2*)(Pb + poffn + lane8);
        int poff2 = chars[t + 2];

        // two dot products, 2 packed accumulator chains each
        f32x2 A0, A1, B0, B1;
        pkmul(A0, wh0p[0], hp[0]);
        pkmul(A1, wh0p[1], hp[1]);
        pkmul(B0, wh1p[0], hp[0]);
        pkmul(B1, wh1p[1], hp[1]);
        #pragma unroll
        for (int k = 2; k < 12; k += 2) {
            pkfma(A0, wh0p[k],     hp[k]);
            pkfma(A1, wh0p[k + 1], hp[k + 1]);
            pkfma(B0, wh1p[k],     hp[k]);
            pkfma(B1, wh1p[k + 1], hp[k + 1]);
        }
        pkfma(A0, wh0p[12], hp[12]);
        pkfma(B0, wh1p[12], hp[12]);
        f32x2 sa = A0 + A1;
        f32x2 sb = B0 + B1;
        const float a0s = sa.x + sa.y + pa.x;   // prescaled for exp2
        const float a1s = sb.x + sb.y + pa.y;

        // activations
        float y0 = __builtin_amdgcn_rcpf(1.0f + __builtin_amdgcn_exp2f(a0s));
        float y1 = fmaf(__builtin_amdgcn_rcpf(1.0f + __builtin_amdgcn_exp2f(a1s)),
                        s1, d1);

        // i*g crosses lanes: lane 26+j pulls y0*y1 from lane j
        float pr = y0 * y1;
        float pp = __int_as_float(
            __builtin_amdgcn_ds_bpermute(bpaddr, __float_as_int(pr)));

        // c,h update (lane-local in lanes 26..51; junk elsewhere)
        c = fmaf(y0, c, pp);
        float th = fmaf(__builtin_amdgcn_rcpf(
                            1.0f + __builtin_amdgcn_exp2f(c * (-2.0f * LOG2E))),
                        2.0f, -1.0f);
        hbuf[hidx] = y1 * th;

        pa = pn; poffn = poff2;
    }

    __syncthreads();

    // ---- final linear: out[b, j] = W_lin[j]·h + b_lin[j] ----
    if (l < H) {
        float acc = b_lin[l];
        #pragma unroll
        for (int k = 0; k < H; ++k)
            acc = fmaf(W_lin[l * H + k], hbuf[k], acc);
        out[(size_t)b * H + l] = acc;
    }
}

extern "C" void kernel_launch(void* const* d_in, const int* in_sizes, int n_in,
                              void* d_out, int out_size, void* d_ws, size_t ws_size,
                              hipStream_t stream) {
    const int*   x     = (const int*)d_in[0];
    const float* E     = (const float*)d_in[1];
    const float* W_ih  = (const float*)d_in[2];
    const float* W_hh  = (const float*)d_in[3];
    const float* b_ih  = (const float*)d_in[4];
    const float* b_hh  = (const float*)d_in[5];
    const float* W_lin = (const float*)d_in[6];
    const float* b_lin = (const float*)d_in[7];
    float* out = (float*)d_out;

    const int T = 1024;
    const int B = in_sizes[0] / T;   // 2048

    lstm_char_kernel<<<B, 64, 0, stream>>>(x, E, W_ih, W_hh, b_ih, b_hh,
                                           W_lin, b_lin, out, T);
}